// Round 25
// baseline (36.667 us; speedup 1.0000x reference)
//
#include <hip/hip_runtime.h>
#include <math.h>

static constexpr int Bn = 32768;

__host__ __device__ constexpr int tidx(int i, int j) { return i*10 - i*(i+1)/2 + j; } // i<=j (upper packed, 10x10)
__host__ __device__ constexpr int lidx(int i, int j) { return i*(i+1)/2 + j; }        // i>=j (lower packed)

// ---- fused: per-block precompute + build(n-split) + s_Q + tridiag + Sturm + tridiag inv-iter ----
// 256 threads = 64 batches x 4 subs.
__global__ __launch_bounds__(256, 2) void k_main(const float* __restrict__ y,
                                                 const float* __restrict__ bb,
                                                 const float* __restrict__ w,
                                                 const float* __restrict__ lam,
                                                 float* __restrict__ out)
{
  // precompute scratch
  __shared__ float s_bb[24][65];    // bb staged coalesced (pad 65: coprime 32)
  __shared__ float s_w[64], s_sw[64], s_barb[64][25];   // stride 25 (coprime 32)
  __shared__ float s_BtB[64];
  __shared__ float s_M[8][16];      // [A | Iv]
  __shared__ float s_u[8], s_red[96];
  __shared__ float s_wsum, s_q00;
  // main tables
  __shared__ float s_cb[4*520];     // per-sub planes, stride 520
  __shared__ float s_G[64], s_g8[8], s_bw[24];
  __shared__ float s_Q[55][66];

  const int t   = threadIdx.x;
  const bool act = (t < 64);
  const int i8 = (t & 63) >> 3, j8 = t & 7;
  const float lv = lam[0];

  // ---- phase 0: coalesced bb stage + w ----
  for (int i = t; i < 24*64; i += 256) s_bb[i >> 6][i & 63] = bb[i];
  if (act) {
    s_w[t]  = w[t];
    s_sw[t] = sqrtf(fmaxf(w[t], 0.0f));
  }
  __syncthreads();
  if (t == 0) { float a = 0; for (int n = 0; n < 64; n++) a += s_w[n]; s_wsum = a; }
  // b_w partials: 96 threads, 16 n each, from LDS
  if (t < 96) {
    const int km = t % 24, q = t / 24;
    float a = 0;
#pragma unroll
    for (int i = 0; i < 16; i++) a += s_bb[km][q*16 + i] * s_w[q*16 + i];
    s_red[t] = a;
  }
  __syncthreads();
  const float wsum = s_wsum;
  if (t < 24)
    s_bw[t] = (s_red[t] + s_red[24 + t] + s_red[48 + t] + s_red[72 + t]) / wsum;
  __syncthreads();
  if (act)
    for (int km = 0; km < 24; ++km)
      s_barb[t][km] = s_sw[t] * (s_bb[km][t] - s_bw[km]);
  __syncthreads();
  if (act) {
    float a = 0;
    for (int n = 0; n < 64; n++)
      for (int j = 0; j < 3; j++)
        a += s_barb[n][i8*3 + j] * s_barb[n][j8*3 + j];
    s_BtB[t] = a;
  }
  if (act) {                          // s_cb staging early (depends only on s_barb; overlaps GJ stalls)
    float* p = s_cb + (t >> 4)*520 + (t & 15)*32;
    p[0] = s_w[t]; p[1] = 0; p[2] = 0; p[3] = 0;
#pragma unroll
    for (int km = 0; km < 24; km++)
      p[4 + km] = s_sw[t] * s_barb[t][km];
#pragma unroll
    for (int i = 28; i < 32; i++) p[i] = 0;
  }
  __syncthreads();
  if (act) {
    s_M[i8][j8]     = 2.0f * (s_BtB[t] + ((i8 == j8) ? lv : 0.0f));
    s_M[i8][8 + j8] = (i8 == j8) ? 1.0f : 0.0f;
  }
  // Gauss-Jordan, 2 barriers/iter (pivot row pre-read)
#pragma unroll
  for (int k = 0; k < 8; k++) {
    __syncthreads();
    float fk = 0.0f, pivv = 1.0f, rk0 = 0.0f, rk1 = 0.0f;
    if (act) {
      fk   = s_M[i8][k];
      pivv = s_M[k][k];
      rk0  = s_M[k][j8];
      rk1  = s_M[k][8 + j8];
    }
    __syncthreads();
    if (act) {
      const float ip = 1.0f / pivv;
      if (i8 == k) { s_M[k][j8] = rk0 * ip; s_M[k][8 + j8] = rk1 * ip; }
      else {
        const float f = fk * ip;
        s_M[i8][j8]     -= f * rk0;
        s_M[i8][8 + j8] -= f * rk1;
      }
    }
  }
  __syncthreads();
  if (t < 8) {
    float a = 0;
#pragma unroll
    for (int j = 0; j < 8; j++) a += s_M[t][8 + j];
    s_u[t] = a;
  }
  __syncthreads();
  if (t == 0) {
    float s = 0;
#pragma unroll
    for (int j = 0; j < 8; j++) s += s_u[j];
    s_red[0] = s;
  }
  __syncthreads();
  {
    const float s = s_red[0];
    if (t < 8) s_g8[t] = s_u[t] / s;
    if (act) s_G[t] = s_M[i8][8 + j8] - s_u[i8] * s_u[j8] / s;
  }
  __syncthreads();
  if (act) s_red[t] = s_g8[i8] * (s_BtB[t] + ((i8 == j8) ? lv : 0.0f)) * s_g8[j8];
  __syncthreads();
  if (t == 0) {
    float a = 0;
    for (int n = 0; n < 64; n++) a += s_red[n];
    s_q00 = a;
  }
  __syncthreads();
  const float q00v = s_q00;

  // ---- build phase: n-split (inline y loads, r22-proven) ----
  const int lb  = t >> 2;
  const int sub = t & 3;
  const int b   = blockIdx.x * 64 + lb;
  const float* yb = y + (size_t)b * 192;
  float F[24][3];
  float gw[6];
  float ywa[3] = {0, 0, 0};
#pragma unroll
  for (int i = 0; i < 24; i++) { F[i][0] = 0; F[i][1] = 0; F[i][2] = 0; }
#pragma unroll
  for (int i = 0; i < 6; i++) gw[i] = 0;

  const float* plane = s_cb + sub*520;
#pragma unroll
  for (int i4 = 0; i4 < 4; i4++) {
    const int n4 = sub*4 + i4;
    float4 v0 = reinterpret_cast<const float4*>(yb)[n4];
    float4 v1 = reinterpret_cast<const float4*>(yb + 64)[n4];
    float4 v2 = reinterpret_cast<const float4*>(yb + 128)[n4];
    float a0[4] = {v0.x, v0.y, v0.z, v0.w};
    float a1[4] = {v1.x, v1.y, v1.z, v1.w};
    float a2[4] = {v2.x, v2.y, v2.z, v2.w};
#pragma unroll
    for (int l = 0; l < 4; l++) {
      const int ni = 4*i4 + l;
      const float4* row = reinterpret_cast<const float4*>(plane + ni*32);
      float4 c0 = row[0];
      float4 ch[6];
#pragma unroll
      for (int cc = 0; cc < 6; cc++) ch[cc] = row[1 + cc];
      const float cb[24] = {ch[0].x, ch[0].y, ch[0].z, ch[0].w,
                            ch[1].x, ch[1].y, ch[1].z, ch[1].w,
                            ch[2].x, ch[2].y, ch[2].z, ch[2].w,
                            ch[3].x, ch[3].y, ch[3].z, ch[3].w,
                            ch[4].x, ch[4].y, ch[4].z, ch[4].w,
                            ch[5].x, ch[5].y, ch[5].z, ch[5].w};
      float ym0 = a0[l], ym1 = a1[l], ym2 = a2[l];
      float wn  = c0.x;
      float wy0 = wn*ym0, wy1 = wn*ym1, wy2 = wn*ym2;
      ywa[0] += wy0; ywa[1] += wy1; ywa[2] += wy2;
      gw[0] += wy0*ym0; gw[1] += wy0*ym1; gw[2] += wy0*ym2;
      gw[3] += wy1*ym1; gw[4] += wy1*ym2; gw[5] += wy2*ym2;
#pragma unroll
      for (int km = 0; km < 24; km++) {
        F[km][0] += cb[km]*ym0; F[km][1] += cb[km]*ym1; F[km][2] += cb[km]*ym2;
      }
    }
  }
#pragma unroll
  for (int km = 0; km < 24; km++)
#pragma unroll
    for (int m = 0; m < 3; m++) {
      float v = F[km][m];
      v += __shfl_xor(v, 1);
      v += __shfl_xor(v, 2);
      F[km][m] = v;
    }
#pragma unroll
  for (int i = 0; i < 6; i++) { float v = gw[i]; v += __shfl_xor(v, 1); v += __shfl_xor(v, 2); gw[i] = v; }
#pragma unroll
  for (int i = 0; i < 3; i++) { float v = ywa[i]; v += __shfl_xor(v, 1); v += __shfl_xor(v, 2); ywa[i] = v; }

  const float iws = 1.0f / wsum;
  float yw[3] = {ywa[0]*iws, ywa[1]*iws, ywa[2]*iws};
  float Gram[6];
  Gram[0] = gw[0] - ywa[0]*ywa[0]*iws;
  Gram[1] = gw[1] - ywa[0]*ywa[1]*iws;
  Gram[2] = gw[2] - ywa[0]*ywa[2]*iws;
  Gram[3] = gw[3] - ywa[1]*ywa[1]*iws;
  Gram[4] = gw[4] - ywa[1]*ywa[2]*iws;
  Gram[5] = gw[5] - ywa[2]*ywa[2]*iws;

  if (sub == 0) s_Q[0][lb] = q00v;
#pragma unroll
  for (int e = 0; e < 9; e++) {
    const int j = e / 3, m = e % 3;
    float a = 0;
#pragma unroll
    for (int k = 0; k < 8; k++) a += s_g8[k] * F[k*3 + j][m];
    if ((e & 3) == sub) s_Q[tidx(0, 1 + e)][lb] = -a;
  }
  float F6[6][3];
#pragma unroll
  for (int kk = 0; kk < 6; kk++)
#pragma unroll
    for (int m = 0; m < 3; m++) {
      float x01 = (sub & 1) ? F[6 + kk][m]  : F[kk][m];
      float x23 = (sub & 1) ? F[18 + kk][m] : F[12 + kk][m];
      F6[kk][m] = (sub & 2) ? x23 : x01;
    }
  float FGr[2][9];
#pragma unroll
  for (int kk = 0; kk < 2; kk++) {
    float gcol[8];
#pragma unroll
    for (int k = 0; k < 8; k++) {
      float g01 = (sub & 1) ? s_G[k*8 + 2 + kk] : s_G[k*8 + 0 + kk];
      float g23 = (sub & 1) ? s_G[k*8 + 6 + kk] : s_G[k*8 + 4 + kk];
      gcol[k] = (sub & 2) ? g23 : g01;
    }
#pragma unroll
    for (int e = 0; e < 9; e++) {
      const int j = e / 3, m = e % 3;
      float a = 0;
#pragma unroll
      for (int k = 0; k < 8; k++) a += gcol[k] * F[k*3 + j][m];
      FGr[kk][e] = a;
    }
  }
#pragma unroll
  for (int e = 0; e < 9; e++)
#pragma unroll
    for (int f = e; f < 9; f++) {
      const int j = e/3, m = e%3, j2 = f/3, m2 = f%3;
      float p = FGr[0][e] * F6[j2][m2] + FGr[1][e] * F6[3 + j2][m2];
      p += __shfl_xor(p, 1);
      p += __shfl_xor(p, 2);
      if ((tidx(1 + e, 1 + f) & 3) == sub) {
        const float gterm = (j == j2) ? Gram[(m <= m2) ? (m*3 - m*(m+1)/2 + m2) : (m2*3 - m2*(m2+1)/2 + m)] : 0.0f;
        s_Q[tidx(1 + e, 1 + f)][lb] = -2.0f*p + gterm;
      }
    }
  __syncthreads();

  // ---- tridiagonalize (reflectors preserved in Mm columns) ----
  float Mm[55];
#pragma unroll
  for (int i = 0; i < 10; i++)
#pragma unroll
    for (int j = 0; j <= i; j++)
      Mm[lidx(i,j)] = s_Q[tidx(j,i)][lb];

  float tr = 0.0f, hi = Mm[lidx(0,0)];
#pragma unroll
  for (int j = 0; j < 10; j++) {
    tr += Mm[lidx(j,j)];
    hi = fminf(hi, Mm[lidx(j,j)]);
  }

  float ad[10], b2[9], bofd[9];
#pragma unroll
  for (int j = 0; j < 8; j++) {
    float s2 = 0;
#pragma unroll
    for (int i = j + 1; i < 10; i++) s2 += Mm[lidx(i,j)] * Mm[lidx(i,j)];
    const float x0 = Mm[lidx(j+1,j)];
    const float anorm = __builtin_amdgcn_sqrtf(s2);
    const float alpha = (x0 > 0.0f) ? -anorm : anorm;
    const float uu = s2 - alpha * x0;
    const float beta = (uu > 1e-35f) ? __builtin_amdgcn_rcpf(uu) : 0.0f;
    float u[10], p[10];
    u[j+1] = x0 - alpha;
#pragma unroll
    for (int i = j + 2; i < 10; i++) u[i] = Mm[lidx(i,j)];
#pragma unroll
    for (int i = j + 1; i < 10; i++) {
      float acc = 0;
#pragma unroll
      for (int k = j + 1; k < 10; k++) acc += Mm[(i >= k) ? lidx(i,k) : lidx(k,i)] * u[k];
      p[i] = beta * acc;
    }
    float K = 0;
#pragma unroll
    for (int i = j + 1; i < 10; i++) K += u[i] * p[i];
    K *= 0.5f * beta;
#pragma unroll
    for (int i = j + 1; i < 10; i++) p[i] -= K * u[i];
#pragma unroll
    for (int i = j + 1; i < 10; i++)
#pragma unroll
      for (int k = j + 1; k <= i; k++)
        Mm[lidx(i,k)] -= u[i]*p[k] + p[i]*u[k];
    ad[j]   = Mm[lidx(j,j)];
    b2[j]   = s2;
    bofd[j] = alpha;
  }
  ad[8] = Mm[lidx(8,8)];
  ad[9] = Mm[lidx(9,9)];
  bofd[8] = Mm[lidx(9,8)];
  b2[8] = bofd[8] * bofd[8];

  float b2max = b2[0];
#pragma unroll
  for (int i = 1; i < 9; i++) b2max = fmaxf(b2max, b2[i]);
  const float pm = 1e-20f * b2max + 1e-30f;

  // ---- phase A: quaternary Sturm bisection on T (9 rounds == 18 bits; bracket err <= 4% of delta) ----
  float lo = 0.0f;
  const int base = (t & 63) & ~3;
  const float subf = (sub == 0) ? 2.0f : (float)sub;
  for (int round = 0; round < 9; ++round) {
    const float quart = 0.25f * (hi - lo);
    const float mid = lo + quart * subf;
    int neg = 0;
    float d = ad[0] - mid;
    neg += (d < 0.0f) ? 1 : 0;
#pragma unroll
    for (int i = 1; i < 10; i++) {
      d = (fabsf(d) < pm) ? -pm : d;
      d = ad[i] - mid - b2[i-1] * __builtin_amdgcn_rcpf(d);
      neg += (d < 0.0f) ? 1 : 0;
    }
    const int n1 = __shfl(neg, base | 1);
    const int n2 = __shfl(neg, base | 2);
    const int n3 = __shfl(neg, base | 3);
    const float m1 = lo + quart, m2v = lo + 2.0f*quart, m3 = lo + 3.0f*quart;
    const float nlo = (n3 == 0) ? m3 : (n2 == 0) ? m2v : (n1 == 0) ? m1 : lo;
    const float nhi = (n1 > 0) ? m1 : (n2 > 0) ? m2v : (n3 > 0) ? m3 : hi;
    lo = nlo; hi = nhi;
  }

  // ---- phase B: tridiagonal LDLT inverse iteration + Householder back-transform ----
  const float delta = 1e-5f * fabsf(tr) + 1e-30f;
  const float sigma = lo - delta;
  float dt[10], lt[9], idt[10];
  dt[0] = ad[0] - sigma;
#pragma unroll
  for (int i = 0; i < 9; i++) {
    float dd = fmaxf(dt[i], 1e-30f);
    float inv = __builtin_amdgcn_rcpf(dd);
    idt[i] = inv;
    lt[i] = bofd[i] * inv;
    dt[i+1] = ad[i+1] - sigma - lt[i]*bofd[i];
  }
  dt[9] = fmaxf(dt[9], 1e-30f);
  idt[9] = __builtin_amdgcn_rcpf(dt[9]);

  float z[10];
#pragma unroll
  for (int i = 0; i < 10; i++) z[i] = 1.0f;
#pragma unroll
  for (int it = 0; it < 3; ++it) {
#pragma unroll
    for (int i = 1; i < 10; i++) z[i] -= lt[i-1]*z[i-1];
#pragma unroll
    for (int i = 0; i < 10; i++) z[i] *= idt[i];
#pragma unroll
    for (int i = 8; i >= 0; i--) z[i] -= lt[i]*z[i+1];
    float s2 = 0;
#pragma unroll
    for (int i = 0; i < 10; i++) s2 += z[i]*z[i];
    float sc = __builtin_amdgcn_rsqf(s2 + 1e-38f);
#pragma unroll
    for (int i = 0; i < 10; i++) z[i] *= sc;
  }
#pragma unroll
  for (int j = 7; j >= 0; j--) {
    const float x0 = Mm[lidx(j+1,j)];
    const float us = x0 - bofd[j];
    const float uu = b2[j] - bofd[j]*x0;
    const float beta = (uu > 1e-35f) ? __builtin_amdgcn_rcpf(uu) : 0.0f;
    float dot = us * z[j+1];
#pragma unroll
    for (int i = j + 2; i < 10; i++) dot += Mm[lidx(i,j)] * z[i];
    const float f = beta * dot;
    z[j+1] -= f * us;
#pragma unroll
    for (int i = j + 2; i < 10; i++) z[i] -= f * Mm[lidx(i,j)];
  }

  // ---- epilogue: R, c, t ----
  const float inv0 = __builtin_amdgcn_rcpf(z[0]);
  float R[3][3];
#pragma unroll
  for (int r = 0; r < 3; r++)
#pragma unroll
    for (int cc = 0; cc < 3; cc++)
      R[r][cc] = z[1 + 3*cc + r] * inv0;

  float cv[2];
#pragma unroll
  for (int kk = 0; kk < 2; kk++) {
    const int k = sub*2 + kk;
    float a = 0;
#pragma unroll
    for (int e = 0; e < 9; e++) a += z[1 + e] * FGr[kk][e];
    cv[kk] = 2.0f * inv0 * a + s_g8[k];
    out[(size_t)12*Bn + (size_t)b*8 + k] = cv[kk];
  }
  float um0 = s_bw[(sub*2)*3 + 0]*cv[0] + s_bw[(sub*2 + 1)*3 + 0]*cv[1];
  float um1 = s_bw[(sub*2)*3 + 1]*cv[0] + s_bw[(sub*2 + 1)*3 + 1]*cv[1];
  float um2 = s_bw[(sub*2)*3 + 2]*cv[0] + s_bw[(sub*2 + 1)*3 + 2]*cv[1];
  um0 += __shfl_xor(um0, 1); um0 += __shfl_xor(um0, 2);
  um1 += __shfl_xor(um1, 1); um1 += __shfl_xor(um1, 2);
  um2 += __shfl_xor(um2, 1); um2 += __shfl_xor(um2, 2);

#pragma unroll
  for (int r = 0; r < 3; r++)
#pragma unroll
    for (int cc = 0; cc < 3; cc++)
      if (((r*3 + cc) & 3) == sub)
        out[(size_t)b*9 + r*3 + cc] = R[r][cc];
  if (sub == 0) {
#pragma unroll
    for (int r = 0; r < 3; r++)
      out[(size_t)9*Bn + (size_t)b*3 + r] = yw[r] - (R[r][0]*um0 + R[r][1]*um1 + R[r][2]*um2);
  }
}

extern "C" void kernel_launch(void* const* d_in, const int* in_sizes, int n_in,
                              void* d_out, int out_size, void* d_ws, size_t ws_size,
                              hipStream_t stream) {
  const float* y   = (const float*)d_in[0];
  const float* bb  = (const float*)d_in[1];
  const float* w   = (const float*)d_in[2];
  const float* lam = (const float*)d_in[3];
  float* out = (float*)d_out;
  (void)d_ws; (void)ws_size;
  k_main<<<Bn/64, 256, 0, stream>>>(y, bb, w, lam, out);
}

// Round 26
// 35.841 us; speedup vs baseline: 1.0230x; 1.0230x over previous
//
#include <hip/hip_runtime.h>
#include <math.h>

static constexpr int Bn = 32768;

__host__ __device__ constexpr int tidx(int i, int j) { return i*10 - i*(i+1)/2 + j; } // i<=j (upper packed, 10x10)
__host__ __device__ constexpr int lidx(int i, int j) { return i*(i+1)/2 + j; }        // i>=j (lower packed)

// ---- fused: per-block precompute + build(n-split) + s_Q + tridiag + Sturm + tridiag inv-iter ----
// 256 threads = 64 batches x 4 subs.  (round-24 configuration: best measured, 35.9 us)
__global__ __launch_bounds__(256, 2) void k_main(const float* __restrict__ y,
                                                 const float* __restrict__ bb,
                                                 const float* __restrict__ w,
                                                 const float* __restrict__ lam,
                                                 float* __restrict__ out)
{
  // precompute scratch
  __shared__ float s_w[64], s_sw[64], s_barb[64][25];   // stride 25 (coprime 32)
  __shared__ float s_BtB[64];
  __shared__ float s_M[8][16];      // [A | Iv]
  __shared__ float s_u[8], s_red[64];
  __shared__ float s_wsum, s_q00;
  // main tables
  __shared__ float s_cb[4*520];     // per-sub planes, stride 520
  __shared__ float s_G[64], s_g8[8], s_bw[24];
  __shared__ float s_Q[55][66];

  const int t   = threadIdx.x;
  const bool act = (t < 64);
  const int i8 = (t & 63) >> 3, j8 = t & 7;
  const float lv = lam[0];

  // ---- inlined precompute ----
  if (act) {
    s_w[t]  = w[t];
    s_sw[t] = sqrtf(fmaxf(w[t], 0.0f));
  }
  __syncthreads();
  if (t == 0) { float a = 0; for (int n = 0; n < 64; n++) a += s_w[n]; s_wsum = a; }
  __syncthreads();
  const float wsum = s_wsum;
  if (t < 24) {                       // b_w[k*3+m]
    float a = 0;
    for (int n = 0; n < 64; n++) a += bb[t*64 + n] * s_w[n];
    s_bw[t] = a / wsum;
  }
  __syncthreads();
  if (act)
    for (int km = 0; km < 24; ++km)
      s_barb[t][km] = s_sw[t] * (bb[km*64 + t] - s_bw[km]);
  __syncthreads();
  if (act) {
    float a = 0;
    for (int n = 0; n < 64; n++)
      for (int j = 0; j < 3; j++)
        a += s_barb[n][i8*3 + j] * s_barb[n][j8*3 + j];
    s_BtB[t] = a;
  }
  __syncthreads();
  if (act) {
    s_M[i8][j8]     = 2.0f * (s_BtB[t] + ((i8 == j8) ? lv : 0.0f));
    s_M[i8][8 + j8] = (i8 == j8) ? 1.0f : 0.0f;
  }
  // Gauss-Jordan, 2 barriers/iter (pivot row pre-read)
#pragma unroll
  for (int k = 0; k < 8; k++) {
    __syncthreads();
    float fk = 0.0f, pivv = 1.0f, rk0 = 0.0f, rk1 = 0.0f;
    if (act) {
      fk   = s_M[i8][k];
      pivv = s_M[k][k];
      rk0  = s_M[k][j8];
      rk1  = s_M[k][8 + j8];
    }
    __syncthreads();
    if (act) {
      const float ip = 1.0f / pivv;
      if (i8 == k) { s_M[k][j8] = rk0 * ip; s_M[k][8 + j8] = rk1 * ip; }
      else {
        const float f = fk * ip;
        s_M[i8][j8]     -= f * rk0;
        s_M[i8][8 + j8] -= f * rk1;
      }
    }
  }
  __syncthreads();
  if (t < 8) {
    float a = 0;
#pragma unroll
    for (int j = 0; j < 8; j++) a += s_M[t][8 + j];
    s_u[t] = a;
  }
  __syncthreads();
  if (t == 0) {
    float s = 0;
#pragma unroll
    for (int j = 0; j < 8; j++) s += s_u[j];
    s_red[0] = s;
  }
  __syncthreads();
  {
    const float s = s_red[0];
    if (t < 8) s_g8[t] = s_u[t] / s;
    if (act) s_G[t] = s_M[i8][8 + j8] - s_u[i8] * s_u[j8] / s;
  }
  __syncthreads();
  if (act) s_red[t] = s_g8[i8] * (s_BtB[t] + ((i8 == j8) ? lv : 0.0f)) * s_g8[j8];
  __syncthreads();
  if (t == 0) {
    float a = 0;
    for (int n = 0; n < 64; n++) a += s_red[n];
    s_q00 = a;
  }
  if (act) {                          // per-sub plane coefficient row, t = n
    float* p = s_cb + (t >> 4)*520 + (t & 15)*32;
    p[0] = s_w[t]; p[1] = 0; p[2] = 0; p[3] = 0;
#pragma unroll
    for (int km = 0; km < 24; km++)
      p[4 + km] = s_sw[t] * s_barb[t][km];
#pragma unroll
    for (int i = 28; i < 32; i++) p[i] = 0;
  }
  __syncthreads();
  const float q00v = s_q00;

  // ---- build phase: n-split (inline y loads) ----
  const int lb  = t >> 2;
  const int sub = t & 3;
  const int b   = blockIdx.x * 64 + lb;
  const float* yb = y + (size_t)b * 192;
  float F[24][3];
  float gw[6];
  float ywa[3] = {0, 0, 0};
#pragma unroll
  for (int i = 0; i < 24; i++) { F[i][0] = 0; F[i][1] = 0; F[i][2] = 0; }
#pragma unroll
  for (int i = 0; i < 6; i++) gw[i] = 0;

  const float* plane = s_cb + sub*520;
#pragma unroll
  for (int i4 = 0; i4 < 4; i4++) {
    const int n4 = sub*4 + i4;
    float4 v0 = reinterpret_cast<const float4*>(yb)[n4];
    float4 v1 = reinterpret_cast<const float4*>(yb + 64)[n4];
    float4 v2 = reinterpret_cast<const float4*>(yb + 128)[n4];
    float a0[4] = {v0.x, v0.y, v0.z, v0.w};
    float a1[4] = {v1.x, v1.y, v1.z, v1.w};
    float a2[4] = {v2.x, v2.y, v2.z, v2.w};
#pragma unroll
    for (int l = 0; l < 4; l++) {
      const int ni = 4*i4 + l;
      const float4* row = reinterpret_cast<const float4*>(plane + ni*32);
      float4 c0 = row[0];
      float4 ch[6];
#pragma unroll
      for (int cc = 0; cc < 6; cc++) ch[cc] = row[1 + cc];
      const float cb[24] = {ch[0].x, ch[0].y, ch[0].z, ch[0].w,
                            ch[1].x, ch[1].y, ch[1].z, ch[1].w,
                            ch[2].x, ch[2].y, ch[2].z, ch[2].w,
                            ch[3].x, ch[3].y, ch[3].z, ch[3].w,
                            ch[4].x, ch[4].y, ch[4].z, ch[4].w,
                            ch[5].x, ch[5].y, ch[5].z, ch[5].w};
      float ym0 = a0[l], ym1 = a1[l], ym2 = a2[l];
      float wn  = c0.x;
      float wy0 = wn*ym0, wy1 = wn*ym1, wy2 = wn*ym2;
      ywa[0] += wy0; ywa[1] += wy1; ywa[2] += wy2;
      gw[0] += wy0*ym0; gw[1] += wy0*ym1; gw[2] += wy0*ym2;
      gw[3] += wy1*ym1; gw[4] += wy1*ym2; gw[5] += wy2*ym2;
#pragma unroll
      for (int km = 0; km < 24; km++) {
        F[km][0] += cb[km]*ym0; F[km][1] += cb[km]*ym1; F[km][2] += cb[km]*ym2;
      }
    }
  }
#pragma unroll
  for (int km = 0; km < 24; km++)
#pragma unroll
    for (int m = 0; m < 3; m++) {
      float v = F[km][m];
      v += __shfl_xor(v, 1);
      v += __shfl_xor(v, 2);
      F[km][m] = v;
    }
#pragma unroll
  for (int i = 0; i < 6; i++) { float v = gw[i]; v += __shfl_xor(v, 1); v += __shfl_xor(v, 2); gw[i] = v; }
#pragma unroll
  for (int i = 0; i < 3; i++) { float v = ywa[i]; v += __shfl_xor(v, 1); v += __shfl_xor(v, 2); ywa[i] = v; }

  const float iws = 1.0f / wsum;
  float yw[3] = {ywa[0]*iws, ywa[1]*iws, ywa[2]*iws};
  float Gram[6];
  Gram[0] = gw[0] - ywa[0]*ywa[0]*iws;
  Gram[1] = gw[1] - ywa[0]*ywa[1]*iws;
  Gram[2] = gw[2] - ywa[0]*ywa[2]*iws;
  Gram[3] = gw[3] - ywa[1]*ywa[1]*iws;
  Gram[4] = gw[4] - ywa[1]*ywa[2]*iws;
  Gram[5] = gw[5] - ywa[2]*ywa[2]*iws;

  if (sub == 0) s_Q[0][lb] = q00v;
#pragma unroll
  for (int e = 0; e < 9; e++) {
    const int j = e / 3, m = e % 3;
    float a = 0;
#pragma unroll
    for (int k = 0; k < 8; k++) a += s_g8[k] * F[k*3 + j][m];
    if ((e & 3) == sub) s_Q[tidx(0, 1 + e)][lb] = -a;
  }
  float F6[6][3];
#pragma unroll
  for (int kk = 0; kk < 6; kk++)
#pragma unroll
    for (int m = 0; m < 3; m++) {
      float x01 = (sub & 1) ? F[6 + kk][m]  : F[kk][m];
      float x23 = (sub & 1) ? F[18 + kk][m] : F[12 + kk][m];
      F6[kk][m] = (sub & 2) ? x23 : x01;
    }
  float FGr[2][9];
#pragma unroll
  for (int kk = 0; kk < 2; kk++) {
    float gcol[8];
#pragma unroll
    for (int k = 0; k < 8; k++) {
      float g01 = (sub & 1) ? s_G[k*8 + 2 + kk] : s_G[k*8 + 0 + kk];
      float g23 = (sub & 1) ? s_G[k*8 + 6 + kk] : s_G[k*8 + 4 + kk];
      gcol[k] = (sub & 2) ? g23 : g01;
    }
#pragma unroll
    for (int e = 0; e < 9; e++) {
      const int j = e / 3, m = e % 3;
      float a = 0;
#pragma unroll
      for (int k = 0; k < 8; k++) a += gcol[k] * F[k*3 + j][m];
      FGr[kk][e] = a;
    }
  }
#pragma unroll
  for (int e = 0; e < 9; e++)
#pragma unroll
    for (int f = e; f < 9; f++) {
      const int j = e/3, m = e%3, j2 = f/3, m2 = f%3;
      float p = FGr[0][e] * F6[j2][m2] + FGr[1][e] * F6[3 + j2][m2];
      p += __shfl_xor(p, 1);
      p += __shfl_xor(p, 2);
      if ((tidx(1 + e, 1 + f) & 3) == sub) {
        const float gterm = (j == j2) ? Gram[(m <= m2) ? (m*3 - m*(m+1)/2 + m2) : (m2*3 - m2*(m2+1)/2 + m)] : 0.0f;
        s_Q[tidx(1 + e, 1 + f)][lb] = -2.0f*p + gterm;
      }
    }
  __syncthreads();

  // ---- tridiagonalize (reflectors preserved in Mm columns) ----
  float Mm[55];
#pragma unroll
  for (int i = 0; i < 10; i++)
#pragma unroll
    for (int j = 0; j <= i; j++)
      Mm[lidx(i,j)] = s_Q[tidx(j,i)][lb];

  float tr = 0.0f, hi = Mm[lidx(0,0)];
#pragma unroll
  for (int j = 0; j < 10; j++) {
    tr += Mm[lidx(j,j)];
    hi = fminf(hi, Mm[lidx(j,j)]);
  }

  float ad[10], b2[9], bofd[9];
#pragma unroll
  for (int j = 0; j < 8; j++) {
    float s2 = 0;
#pragma unroll
    for (int i = j + 1; i < 10; i++) s2 += Mm[lidx(i,j)] * Mm[lidx(i,j)];
    const float x0 = Mm[lidx(j+1,j)];
    const float anorm = __builtin_amdgcn_sqrtf(s2);
    const float alpha = (x0 > 0.0f) ? -anorm : anorm;
    const float uu = s2 - alpha * x0;
    const float beta = (uu > 1e-35f) ? __builtin_amdgcn_rcpf(uu) : 0.0f;
    float u[10], p[10];
    u[j+1] = x0 - alpha;
#pragma unroll
    for (int i = j + 2; i < 10; i++) u[i] = Mm[lidx(i,j)];
#pragma unroll
    for (int i = j + 1; i < 10; i++) {
      float acc = 0;
#pragma unroll
      for (int k = j + 1; k < 10; k++) acc += Mm[(i >= k) ? lidx(i,k) : lidx(k,i)] * u[k];
      p[i] = beta * acc;
    }
    float K = 0;
#pragma unroll
    for (int i = j + 1; i < 10; i++) K += u[i] * p[i];
    K *= 0.5f * beta;
#pragma unroll
    for (int i = j + 1; i < 10; i++) p[i] -= K * u[i];
#pragma unroll
    for (int i = j + 1; i < 10; i++)
#pragma unroll
      for (int k = j + 1; k <= i; k++)
        Mm[lidx(i,k)] -= u[i]*p[k] + p[i]*u[k];
    ad[j]   = Mm[lidx(j,j)];
    b2[j]   = s2;
    bofd[j] = alpha;
  }
  ad[8] = Mm[lidx(8,8)];
  ad[9] = Mm[lidx(9,9)];
  bofd[8] = Mm[lidx(9,8)];
  b2[8] = bofd[8] * bofd[8];

  float b2max = b2[0];
#pragma unroll
  for (int i = 1; i < 9; i++) b2max = fmaxf(b2max, b2[i]);
  const float pm = 1e-20f * b2max + 1e-30f;

  // ---- phase A: quaternary Sturm bisection on T (9 rounds == 18 bits) ----
  float lo = 0.0f;
  const int base = (t & 63) & ~3;
  const float subf = (sub == 0) ? 2.0f : (float)sub;
  for (int round = 0; round < 9; ++round) {
    const float quart = 0.25f * (hi - lo);
    const float mid = lo + quart * subf;
    int neg = 0;
    float d = ad[0] - mid;
    neg += (d < 0.0f) ? 1 : 0;
#pragma unroll
    for (int i = 1; i < 10; i++) {
      d = (fabsf(d) < pm) ? -pm : d;
      d = ad[i] - mid - b2[i-1] * __builtin_amdgcn_rcpf(d);
      neg += (d < 0.0f) ? 1 : 0;
    }
    const int n1 = __shfl(neg, base | 1);
    const int n2 = __shfl(neg, base | 2);
    const int n3 = __shfl(neg, base | 3);
    const float m1 = lo + quart, m2v = lo + 2.0f*quart, m3 = lo + 3.0f*quart;
    const float nlo = (n3 == 0) ? m3 : (n2 == 0) ? m2v : (n1 == 0) ? m1 : lo;
    const float nhi = (n1 > 0) ? m1 : (n2 > 0) ? m2v : (n3 > 0) ? m3 : hi;
    lo = nlo; hi = nhi;
  }

  // ---- phase B: tridiagonal LDLT inverse iteration + Householder back-transform ----
  const float delta = 1e-5f * fabsf(tr) + 1e-30f;
  const float sigma = lo - delta;
  float dt[10], lt[9], idt[10];
  dt[0] = ad[0] - sigma;
#pragma unroll
  for (int i = 0; i < 9; i++) {
    float dd = fmaxf(dt[i], 1e-30f);
    float inv = __builtin_amdgcn_rcpf(dd);
    idt[i] = inv;
    lt[i] = bofd[i] * inv;
    dt[i+1] = ad[i+1] - sigma - lt[i]*bofd[i];
  }
  dt[9] = fmaxf(dt[9], 1e-30f);
  idt[9] = __builtin_amdgcn_rcpf(dt[9]);

  float z[10];
#pragma unroll
  for (int i = 0; i < 10; i++) z[i] = 1.0f;
#pragma unroll
  for (int it = 0; it < 3; ++it) {
#pragma unroll
    for (int i = 1; i < 10; i++) z[i] -= lt[i-1]*z[i-1];
#pragma unroll
    for (int i = 0; i < 10; i++) z[i] *= idt[i];
#pragma unroll
    for (int i = 8; i >= 0; i--) z[i] -= lt[i]*z[i+1];
    float s2 = 0;
#pragma unroll
    for (int i = 0; i < 10; i++) s2 += z[i]*z[i];
    float sc = __builtin_amdgcn_rsqf(s2 + 1e-38f);
#pragma unroll
    for (int i = 0; i < 10; i++) z[i] *= sc;
  }
#pragma unroll
  for (int j = 7; j >= 0; j--) {
    const float x0 = Mm[lidx(j+1,j)];
    const float us = x0 - bofd[j];
    const float uu = b2[j] - bofd[j]*x0;
    const float beta = (uu > 1e-35f) ? __builtin_amdgcn_rcpf(uu) : 0.0f;
    float dot = us * z[j+1];
#pragma unroll
    for (int i = j + 2; i < 10; i++) dot += Mm[lidx(i,j)] * z[i];
    const float f = beta * dot;
    z[j+1] -= f * us;
#pragma unroll
    for (int i = j + 2; i < 10; i++) z[i] -= f * Mm[lidx(i,j)];
  }

  // ---- epilogue: R, c, t ----
  const float inv0 = __builtin_amdgcn_rcpf(z[0]);
  float R[3][3];
#pragma unroll
  for (int r = 0; r < 3; r++)
#pragma unroll
    for (int cc = 0; cc < 3; cc++)
      R[r][cc] = z[1 + 3*cc + r] * inv0;

  float cv[2];
#pragma unroll
  for (int kk = 0; kk < 2; kk++) {
    const int k = sub*2 + kk;
    float a = 0;
#pragma unroll
    for (int e = 0; e < 9; e++) a += z[1 + e] * FGr[kk][e];
    cv[kk] = 2.0f * inv0 * a + s_g8[k];
    out[(size_t)12*Bn + (size_t)b*8 + k] = cv[kk];
  }
  float um0 = s_bw[(sub*2)*3 + 0]*cv[0] + s_bw[(sub*2 + 1)*3 + 0]*cv[1];
  float um1 = s_bw[(sub*2)*3 + 1]*cv[0] + s_bw[(sub*2 + 1)*3 + 1]*cv[1];
  float um2 = s_bw[(sub*2)*3 + 2]*cv[0] + s_bw[(sub*2 + 1)*3 + 2]*cv[1];
  um0 += __shfl_xor(um0, 1); um0 += __shfl_xor(um0, 2);
  um1 += __shfl_xor(um1, 1); um1 += __shfl_xor(um1, 2);
  um2 += __shfl_xor(um2, 1); um2 += __shfl_xor(um2, 2);

#pragma unroll
  for (int r = 0; r < 3; r++)
#pragma unroll
    for (int cc = 0; cc < 3; cc++)
      if (((r*3 + cc) & 3) == sub)
        out[(size_t)b*9 + r*3 + cc] = R[r][cc];
  if (sub == 0) {
#pragma unroll
    for (int r = 0; r < 3; r++)
      out[(size_t)9*Bn + (size_t)b*3 + r] = yw[r] - (R[r][0]*um0 + R[r][1]*um1 + R[r][2]*um2);
  }
}

extern "C" void kernel_launch(void* const* d_in, const int* in_sizes, int n_in,
                              void* d_out, int out_size, void* d_ws, size_t ws_size,
                              hipStream_t stream) {
  const float* y   = (const float*)d_in[0];
  const float* bb  = (const float*)d_in[1];
  const float* w   = (const float*)d_in[2];
  const float* lam = (const float*)d_in[3];
  float* out = (float*)d_out;
  (void)d_ws; (void)ws_size;
  k_main<<<Bn/64, 256, 0, stream>>>(y, bb, w, lam, out);
}